// Round 4
// baseline (1157.774 us; speedup 1.0000x reference)
//
#include <hip/hip_runtime.h>
#include <hip/hip_bf16.h>
#include <math.h>

#define DD 768
#define QN 64
#define TN 128
#define BK 64
#define NSLICE 12
#define TOPK 10
#define CAND 32
#define NBLK 768

typedef short bf16x8 __attribute__((ext_vector_type(8)));
typedef float f32x4  __attribute__((ext_vector_type(4)));

// float -> bf16 round-to-nearest-even (bit exact, used for queries)
__device__ __forceinline__ unsigned short f2bf(float f) {
    unsigned int u = __float_as_uint(f);
    u = (u + 0x7fffu + ((u >> 16) & 1u)) >> 16;
    return (unsigned short)u;
}

// pack 2 floats -> 2 bf16 (compiler emits v_cvt_pk_bf16_f32)
__device__ __forceinline__ unsigned pk2(float a, float b) {
    union { __hip_bfloat162 h2; unsigned u; } cv;
    cv.h2.x = __float2bfloat16(a);
    cv.h2.y = __float2bfloat16(b);
    return cv.u;
}

// ---------------------------------------------------------------------------
// top-10 sorted insert (descending), fully unrolled -> stays in VGPRs
// ---------------------------------------------------------------------------
__device__ __forceinline__ void topk_insert(float (&sc)[TOPK], int (&id)[TOPK],
                                            float v, int nid) {
    if (v <= sc[TOPK - 1]) return;
#pragma unroll
    for (int j = TOPK - 1; j >= 1; --j) {
        bool gtj   = v > sc[j];
        bool gtjm1 = v > sc[j - 1];
        float cs = gtjm1 ? sc[j - 1] : v;
        int   ci = gtjm1 ? id[j - 1] : nid;
        sc[j] = gtj ? cs : sc[j];
        id[j] = gtj ? ci : id[j];
    }
    bool gt0 = v > sc[0];
    sc[0] = gt0 ? v : sc[0];
    id[0] = gt0 ? nid : id[0];
}

// ---------------------------------------------------------------------------
// Phase 0: L2-normalize queries (fp32 math), emit bf16 [64][768]
// ---------------------------------------------------------------------------
__global__ void qnorm_kernel(const float* __restrict__ q,
                             unsigned short* __restrict__ qn) {
    const int row = blockIdx.x;
    const int t = threadIdx.x;  // 256
    float vals[3];
    float s = 0.f;
#pragma unroll
    for (int i = 0; i < 3; ++i) {
        vals[i] = q[row * DD + i * 256 + t];
        s += vals[i] * vals[i];
    }
#pragma unroll
    for (int o = 32; o; o >>= 1) s += __shfl_down(s, o);
    __shared__ float red[4];
    if ((t & 63) == 0) red[t >> 6] = s;
    __syncthreads();
    float tot = red[0] + red[1] + red[2] + red[3];
    float inv = 1.f / fmaxf(sqrtf(tot), 1e-12f);
#pragma unroll
    for (int i = 0; i < 3; ++i)
        qn[row * DD + i * 256 + t] = f2bf(vals[i] * inv);
}

// ---------------------------------------------------------------------------
// Phase 1: MFMA bf16 approx scores (filter). 128-doc tiles, double-buffered
// bf16 doc tile in LDS (one barrier/slice, loads issued post-barrier so no
// barrier drains an in-flight prefetch), A-frags direct from L2-resident qn,
// doc norms via shfl_xor, all-thread parallel top-10 scan.
// ---------------------------------------------------------------------------
__global__ __launch_bounds__(256, 3)
void score_kernel(const unsigned short* __restrict__ qn,
                  const float* __restrict__ docs,
                  float* __restrict__ cand_sc, int* __restrict__ cand_id,
                  int Ndocs, int ntiles) {
    // arena: bt0[16K] | bt1[16K]  overlaid by  scb[128][68] f32 (34816B)
    //        and by final-merge lists (20480B)
    __shared__ float arena_f[8832];   // 35328 B
    __shared__ float dinv[TN];
    char* arena = (char*)arena_f;
    unsigned short* bt0 = (unsigned short*)arena;
    unsigned short* bt1 = (unsigned short*)(arena + 16384);
    float* scb = arena_f;

    const int tid  = threadIdx.x;
    const int lane = tid & 63;
    const int wv   = tid >> 6;     // wave id 0..3 -> doc cols [wv*32, wv*32+32)
    const int r0   = tid >> 3;     // staging base row (0..31)
    const int c8   = tid & 7;      // 32B fp32 chunk column
    const int fr   = lane & 15;    // frag row/col within 16
    const int fk   = lane >> 4;    // frag k-subchunk 0..3
    const int sq   = wv * 16 + (lane >> 2);  // scan query 0..63
    const int scq  = lane & 3;               // scan doc quarter
    const int sqsw = sq ^ ((scq & 1) << 4);  // swizzled scb q-index

    float sc[TOPK];
    int   id[TOPK];
#pragma unroll
    for (int j = 0; j < TOPK; ++j) { sc[j] = -INFINITY; id[j] = 0; }

    float4 rb0[4][2], rb1[4][2];   // 2-slice-deep doc prefetch registers

    auto LOADB = [&](float4 (&r)[4][2], int dg, int kk, bool full) {
        if (full) {
#pragma unroll
            for (int i = 0; i < 4; ++i) {
                const float* p = docs + (size_t)(dg + i * 32 + r0) * DD + kk + c8 * 8;
                r[i][0] = *(const float4*)(p);
                r[i][1] = *(const float4*)(p + 4);
            }
        } else {
#pragma unroll
            for (int i = 0; i < 4; ++i) {
                int gd = dg + i * 32 + r0;
                if (gd < Ndocs) {
                    const float* p = docs + (size_t)gd * DD + kk + c8 * 8;
                    r[i][0] = *(const float4*)(p);
                    r[i][1] = *(const float4*)(p + 4);
                } else {
                    r[i][0] = make_float4(0.f, 0.f, 0.f, 0.f);
                    r[i][1] = make_float4(0.f, 0.f, 0.f, 0.f);
                }
            }
        }
    };

    // ---- prologue: prefetch slices 0,1 of first tile ----
    int tile = blockIdx.x;
    if (tile < ntiles) {
        bool f0 = tile * TN + TN <= Ndocs;
        LOADB(rb0, tile * TN, 0, f0);
        LOADB(rb1, tile * TN, BK, f0);
    }

    for (; tile < ntiles; tile += gridDim.x) {
        const int d0g = tile * TN;
        const bool full = d0g + TN <= Ndocs;
        const int ntile = tile + gridDim.x;
        const bool has_next = ntile < ntiles;
        const int nd0 = ntile * TN;
        const bool nfull = nd0 + TN <= Ndocs;

        f32x4 acc[4][2];
#pragma unroll
        for (int m = 0; m < 4; ++m)
#pragma unroll
            for (int n = 0; n < 2; ++n)
#pragma unroll
                for (int v = 0; v < 4; ++v) acc[m][n][v] = 0.f;
        float dnp[4] = {0.f, 0.f, 0.f, 0.f};

        auto STORE = [&](float4 (&r)[4][2], unsigned short* buf) {
#pragma unroll
            for (int i = 0; i < 4; ++i) {
                int row = i * 32 + r0;
                float4 a = r[i][0], b = r[i][1];
                dnp[i] += a.x * a.x + a.y * a.y + a.z * a.z + a.w * a.w
                        + b.x * b.x + b.y * b.y + b.z * b.z + b.w * b.w;
                uint4 w;
                w.x = pk2(a.x, a.y);
                w.y = pk2(a.z, a.w);
                w.z = pk2(b.x, b.y);
                w.w = pk2(b.z, b.w);
                int off = (row * 128 + c8 * 16) ^ ((row & 7) << 4);
                *(uint4*)((char*)buf + off) = w;
            }
        };

        auto MM = [&](const unsigned short* buf, int kk) {
#pragma unroll
            for (int kc = 0; kc < 2; ++kc) {
                bf16x8 af[4];
#pragma unroll
                for (int m = 0; m < 4; ++m)
                    af[m] = *(const bf16x8*)(qn + (m * 16 + fr) * DD + kk + kc * 32 + fk * 8);
                bf16x8 bfr[2];
#pragma unroll
                for (int n = 0; n < 2; ++n) {
                    int row = wv * 32 + n * 16 + fr;
                    int off = (row * 128 + kc * 64 + fk * 16) ^ ((row & 7) << 4);
                    bfr[n] = *(const bf16x8*)((const char*)buf + off);
                }
#pragma unroll
                for (int m = 0; m < 4; ++m)
#pragma unroll
                    for (int n = 0; n < 2; ++n)
                        acc[m][n] = __builtin_amdgcn_mfma_f32_16x16x32_bf16(
                            af[m], bfr[n], acc[m][n], 0, 0, 0);
            }
        };

        // ---- K loop: 12 slices, unrolled by 2 for static rb ping-pong ----
        for (int s = 0; s < NSLICE; s += 2) {
            STORE(rb0, bt0);
            __syncthreads();                       // bt0 staged; vmem queue empty here
            if (s + 2 < NSLICE) LOADB(rb0, d0g, (s + 2) * BK, full);
            MM(bt0, s * BK);

            STORE(rb1, bt1);                       // other buffer: no barrier hazard
            __syncthreads();
            if (s + 3 < NSLICE) LOADB(rb1, d0g, (s + 3) * BK, full);
            MM(bt1, s * BK + BK);
        }

        // ---- doc norms: shfl-xor reduce over the 8 k-chunk lanes ----
#pragma unroll
        for (int i = 0; i < 4; ++i) {
            float s = dnp[i];
            s += __shfl_xor(s, 1);
            s += __shfl_xor(s, 2);
            s += __shfl_xor(s, 4);
            if (c8 == 0) dinv[i * 32 + r0] = 1.f / fmaxf(sqrtf(s), 1e-12f);
        }
        __syncthreads();   // dinv visible; all MFMA reads of bt0/bt1 done

        // ---- scale + scatter scores doc-major into scb (overlays bt) ----
        {
            const int fq4 = (lane >> 4) * 4;
#pragma unroll
            for (int n = 0; n < 2; ++n) {
                int dcol = wv * 32 + n * 16 + fr;
                float di = dinv[dcol];
                int swz = ((dcol >> 5) & 1) << 4;
#pragma unroll
                for (int m = 0; m < 4; ++m) {
                    f32x4 v = acc[m][n];
                    float4 o = make_float4(v[0] * di, v[1] * di, v[2] * di, v[3] * di);
                    *(float4*)(scb + dcol * 68 + ((m * 16 + fq4) ^ swz)) = o;
                }
            }
        }
        __syncthreads();

        // ---- prefetch next tile's first two slices (in flight across scan) ----
        if (has_next) {
            LOADB(rb0, nd0, 0, nfull);
            LOADB(rb1, nd0, BK, nfull);
        }

        // ---- parallel scan: each thread top-10 over (query sq, quarter scq) ----
        {
            int rem = Ndocs - d0g;
            if (rem > TN) rem = TN;
            int lim = rem - scq * 32;
            lim = lim < 0 ? 0 : (lim > 32 ? 32 : lim);
            for (int i = 0; i < lim; ++i) {
                int j = scq * 32 + i;
                topk_insert(sc, id, scb[j * 68 + sqsw], d0g + j);
            }
        }
        __syncthreads();   // scb reads done before next tile's STORE overwrites
    }

    // ---- in-block merge: 4 quarter-lists per query -> one top-10 ----
    {
        float* lsc = arena_f;                 // [256][10] floats
        int*   lid = (int*)(arena + 10240);   // [256][10] ints
#pragma unroll
        for (int j = 0; j < TOPK; ++j) {
            lsc[tid * TOPK + j] = sc[j];
            lid[tid * TOPK + j] = id[j];
        }
        __syncthreads();
        if (tid < QN) {
            float fs[TOPK];
            int   fi[TOPK];
#pragma unroll
            for (int j = 0; j < TOPK; ++j) { fs[j] = -INFINITY; fi[j] = 0; }
            for (int c = 0; c < 4; ++c) {
                int base = (tid * 4 + c) * TOPK;
                for (int j = 0; j < TOPK; ++j) {
                    float v = lsc[base + j];
                    if (v <= fs[TOPK - 1]) break;   // lists sorted desc
                    topk_insert(fs, fi, v, lid[base + j]);
                }
            }
            size_t gbase = ((size_t)blockIdx.x * QN + tid) * TOPK;
#pragma unroll
            for (int j = 0; j < TOPK; ++j) {
                cand_sc[gbase + j] = fs[j];
                cand_id[gbase + j] = fi[j];
            }
        }
    }
}

// ---------------------------------------------------------------------------
// Phase 2: per query, reduce nlists sorted 10-lists -> global approx top-32.
// Level 0: each thread LDS-insertion-merges its ceil(n/256) lists (<=30 elems,
// no truncation). Then two-pointer tree 128->1 keeping 32.
// ---------------------------------------------------------------------------
__global__ __launch_bounds__(256)
void merge32_kernel(const float* __restrict__ cand_sc,
                    const int* __restrict__ cand_id,
                    int* __restrict__ cand32, int nlists) {
    const int q = blockIdx.x;
    const int t = threadIdx.x;  // 256
    __shared__ float lsc[256 * CAND];  // 32 KB
    __shared__ int   lid[256 * CAND];  // 32 KB
    const int base = t * CAND;
#pragma unroll
    for (int j = 0; j < CAND; ++j) { lsc[base + j] = -INFINITY; lid[base + j] = 0; }

    for (int b = t; b < nlists; b += 256) {
        size_t g = ((size_t)b * QN + q) * TOPK;
        for (int j = 0; j < TOPK; ++j) {
            float v = cand_sc[g + j];
            if (v <= lsc[base + CAND - 1]) break;   // list sorted desc
            int idv = cand_id[g + j];
            int p = CAND - 1;
            while (p > 0 && lsc[base + p - 1] < v) {
                lsc[base + p] = lsc[base + p - 1];
                lid[base + p] = lid[base + p - 1];
                --p;
            }
            lsc[base + p] = v;
            lid[base + p] = idv;
        }
    }
    __syncthreads();

    for (int s = 128; s >= 1; s >>= 1) {
        if (t < s) {
            int ia = 0, ib = 0;
            float rs[CAND];
            int   ri[CAND];
#pragma unroll
            for (int j = 0; j < CAND; ++j) {
                float va = lsc[t * CAND + ia];
                float vb = lsc[(t + s) * CAND + ib];
                bool ta = va >= vb;
                rs[j] = ta ? va : vb;
                ri[j] = ta ? lid[t * CAND + ia] : lid[(t + s) * CAND + ib];
                ia += ta ? 1 : 0;
                ib += ta ? 0 : 1;
            }
#pragma unroll
            for (int j = 0; j < CAND; ++j) {
                lsc[t * CAND + j] = rs[j];
                lid[t * CAND + j] = ri[j];
            }
        }
        __syncthreads();
    }
    if (t < CAND) cand32[q * CAND + t] = lid[t];
}

// ---------------------------------------------------------------------------
// Phase 3: exact fp32 rescore of 32 candidates per query (double accumulate),
// final top-10 by rank-count with (score desc, index asc) tie-break.
// ---------------------------------------------------------------------------
__global__ __launch_bounds__(256)
void rescore_kernel(const float* __restrict__ q, const float* __restrict__ docs,
                    const int* __restrict__ cand32, float* __restrict__ out,
                    int score_off) {
    const int qi = blockIdx.x;
    const int t = threadIdx.x, lane = t & 63, wv = t >> 6;
    __shared__ float qbuf[DD];
    __shared__ float red[4];
    __shared__ float csc[CAND];
    __shared__ int   cid[CAND];

    float v[3];
    float ss = 0.f;
#pragma unroll
    for (int i = 0; i < 3; ++i) {
        v[i] = q[qi * DD + i * 256 + t];
        ss += v[i] * v[i];
    }
#pragma unroll
    for (int o = 32; o; o >>= 1) ss += __shfl_down(ss, o);
    if (lane == 0) red[wv] = ss;
    __syncthreads();
    float qnorm = fmaxf(sqrtf(red[0] + red[1] + red[2] + red[3]), 1e-12f);
#pragma unroll
    for (int i = 0; i < 3; ++i) qbuf[i * 256 + t] = v[i] / qnorm;
    __syncthreads();

    for (int c = wv; c < CAND; c += 4) {
        const int d = cand32[qi * CAND + c];
        const float* dp = docs + (size_t)d * DD;
        float dss = 0.f;
#pragma unroll
        for (int j = 0; j < 3; ++j) {
            float4 dv = *(const float4*)(dp + j * 256 + lane * 4);
            dss += dv.x * dv.x + dv.y * dv.y + dv.z * dv.z + dv.w * dv.w;
        }
#pragma unroll
        for (int o = 32; o; o >>= 1) dss += __shfl_down(dss, o);
        dss = __shfl(dss, 0);
        float dnorm = fmaxf(sqrtf(dss), 1e-12f);
        double dot = 0.0;
#pragma unroll
        for (int j = 0; j < 3; ++j) {
            float4 dv = *(const float4*)(dp + j * 256 + lane * 4);
            float4 qv = *(const float4*)(qbuf + j * 256 + lane * 4);
            float d0 = dv.x / dnorm, d1 = dv.y / dnorm;
            float d2 = dv.z / dnorm, d3 = dv.w / dnorm;
            dot += (double)d0 * qv.x + (double)d1 * qv.y
                 + (double)d2 * qv.z + (double)d3 * qv.w;
        }
#pragma unroll
        for (int o = 32; o; o >>= 1) dot += __shfl_down(dot, o);
        if (lane == 0) { csc[c] = (float)dot; cid[c] = d; }
    }
    __syncthreads();

    if (t < CAND) {
        float s = csc[t];
        int myid = cid[t];
        int rank = 0;
        for (int j = 0; j < CAND; ++j) {
            float sj = csc[j];
            int ij = cid[j];
            rank += ((sj > s) || (sj == s && ij < myid)) ? 1 : 0;
        }
        if (rank < TOPK) {
            out[qi * TOPK + rank] = (float)myid;
            out[score_off + qi * TOPK + rank] = s;
        }
    }
}

// ---------------------------------------------------------------------------
extern "C" void kernel_launch(void* const* d_in, const int* in_sizes, int n_in,
                              void* d_out, int out_size, void* d_ws, size_t ws_size,
                              hipStream_t stream) {
    const float* q    = (const float*)d_in[0];
    const float* docs = (const float*)d_in[1];
    const int N = in_sizes[1] / DD;   // 500000

    // ws layout: qn bf16 [64*768] | cand32 int [64*32] | cand_sc f32 | cand_id i32
    unsigned short* qn = (unsigned short*)d_ws;
    const size_t qbytes = (size_t)QN * DD * 2;
    int* cand32 = (int*)((char*)d_ws + qbytes);
    const size_t c32bytes = (size_t)QN * CAND * 4;

    size_t used = qbytes + c32bytes;
    size_t avail = (ws_size > used) ? (ws_size - used) : 0;
    size_t per_list = (size_t)QN * TOPK * 8;
    int ntiles = (N + TN - 1) / TN;
    int nblk = NBLK;
    if ((size_t)nblk * per_list > avail) nblk = (int)(avail / per_list);
    if (nblk < 1) nblk = 1;
    if (nblk > ntiles) nblk = ntiles;

    float* cand_sc = (float*)((char*)d_ws + used);
    int*   cand_id = (int*)(cand_sc + (size_t)nblk * QN * TOPK);

    hipLaunchKernelGGL(qnorm_kernel, dim3(QN), dim3(256), 0, stream, q, qn);
    hipLaunchKernelGGL(score_kernel, dim3(nblk), dim3(256), 0, stream,
                       qn, docs, cand_sc, cand_id, N, ntiles);
    hipLaunchKernelGGL(merge32_kernel, dim3(QN), dim3(256), 0, stream,
                       cand_sc, cand_id, cand32, nblk);
    hipLaunchKernelGGL(rescore_kernel, dim3(QN), dim3(256), 0, stream,
                       q, docs, cand32, (float*)d_out, out_size / 2);
}